// Round 2
// baseline (1200.049 us; speedup 1.0000x reference)
//
#include <hip/hip_runtime.h>
#include <hip/hip_bf16.h>
#include <cstdint>

#define NTOK 4096
#define DIM 1024
#define NEXP 8
#define HID 4096
#define TWO_H 8192
#define RCAP (NTOK*NEXP)
#define TOTROWS (NTOK*2)
#define ROWPAD (TOTROWS + 128)

typedef __attribute__((ext_vector_type(8))) short short8;
typedef __attribute__((ext_vector_type(4))) float f32x4;

__device__ __forceinline__ void async16(const void* g, void* l) {
    __builtin_amdgcn_global_load_lds(
        (const __attribute__((address_space(1))) unsigned int*)g,
        (__attribute__((address_space(3))) unsigned int*)l, 16, 0, 0);
}

__device__ __forceinline__ unsigned int packbf2(float a, float b) {
    union { __hip_bfloat16 h[2]; unsigned int u; } t;
    t.h[0] = __float2bfloat16(a); t.h[1] = __float2bfloat16(b);
    return t.u;
}

__device__ __forceinline__ short8 cvtfrag(float4 f0, float4 f1) {
    union { unsigned int u[4]; short8 s; } t;
    t.u[0] = packbf2(f0.x, f0.y); t.u[1] = packbf2(f0.z, f0.w);
    t.u[2] = packbf2(f1.x, f1.y); t.u[3] = packbf2(f1.z, f1.w);
    return t.s;
}

// ---------------- gate: logits, top-2, probs, routing lists ----------------
__global__ __launch_bounds__(256) void gate_kernel(
    const float* __restrict__ x, const float* __restrict__ Wg,
    float* __restrict__ p, float* __restrict__ topw,
    int* __restrict__ tok_list, int* __restrict__ klist, int* __restrict__ counts) {
    int n = blockIdx.x * 4 + (threadIdx.x >> 6);
    int lane = threadIdx.x & 63;
    const float* xr = x + (size_t)n * DIM;
    float acc[8];
#pragma unroll
    for (int e = 0; e < 8; e++) acc[e] = 0.f;
#pragma unroll
    for (int i = 0; i < 16; i++) {
        int d = i * 64 + lane;
        float xv = xr[d];
        const float4* wrow = (const float4*)(Wg + (size_t)d * 8);
        float4 w0 = wrow[0], w1 = wrow[1];
        acc[0] += xv * w0.x; acc[1] += xv * w0.y; acc[2] += xv * w0.z; acc[3] += xv * w0.w;
        acc[4] += xv * w1.x; acc[5] += xv * w1.y; acc[6] += xv * w1.z; acc[7] += xv * w1.w;
    }
#pragma unroll
    for (int m = 1; m < 64; m <<= 1) {
#pragma unroll
        for (int e = 0; e < 8; e++) acc[e] += __shfl_xor(acc[e], m, 64);
    }
    if (lane == 0) {
        int i0 = 0; float v0 = acc[0];
#pragma unroll
        for (int e = 1; e < 8; e++) if (acc[e] > v0) { v0 = acc[e]; i0 = e; }
        int i1 = -1; float v1 = -1e30f;
#pragma unroll
        for (int e = 0; e < 8; e++) if (e != i0 && acc[e] > v1) { v1 = acc[e]; i1 = e; }
        float ee = __expf(v1 - v0);
        float s = 1.f + ee;
        topw[2 * n] = 1.f / s;
        topw[2 * n + 1] = ee / s;
        float se = 0.f; float pe[8];
#pragma unroll
        for (int e = 0; e < 8; e++) { pe[e] = __expf(acc[e] - v0); se += pe[e]; }
        float inv = 1.f / se;
#pragma unroll
        for (int e = 0; e < 8; e++) p[(size_t)n * 8 + e] = pe[e] * inv;
        int p0 = atomicAdd(&counts[i0], 1);
        tok_list[i0 * NTOK + p0] = n; klist[i0 * NTOK + p0] = 0;
        int p1 = atomicAdd(&counts[i1], 1);
        tok_list[i1 * NTOK + p1] = n; klist[i1 * NTOK + p1] = 1;
    }
}

// ---------------- finalize: offsets prefix + aux loss ----------------
__global__ __launch_bounds__(256) void finalize_kernel(const float* __restrict__ p,
                                                       const int* __restrict__ counts,
                                                       int* __restrict__ offsets,
                                                       float* __restrict__ aux_out) {
    __shared__ float red[256];
    int t = threadIdx.x;
    float a = 0.f;
    for (int i = t; i < NTOK * NEXP; i += 256) a += p[i];
    red[t] = a;
    __syncthreads();
    if (t < 8) {
        float s = 0.f;
        for (int j = t; j < 256; j += 8) s += red[j];
        red[t] = s;
    }
    __syncthreads();
    if (t == 0) {
        int off = 0; float aux = 0.f;
        for (int e = 0; e < 8; e++) {
            offsets[e] = off;
            aux += ((float)counts[e] / (float)NTOK) * (red[e] / (float)NTOK);
            off += counts[e];
        }
        offsets[8] = off;
        aux_out[0] = 8.f * aux;
    }
}

// ---------------- pack: gather selected rows, convert to bf16 ----------------
__global__ __launch_bounds__(256) void pack_kernel(const float* __restrict__ x,
                                                   const int* __restrict__ tok_list,
                                                   const int* __restrict__ klist,
                                                   const int* __restrict__ counts,
                                                   const int* __restrict__ offsets,
                                                   __hip_bfloat16* __restrict__ xg,
                                                   int* __restrict__ prow) {
    int ci = blockIdx.x * 4 + (threadIdx.x >> 6);
    int lane = threadIdx.x & 63;
    int e = ci >> 12, pos = ci & (NTOK - 1);
    if (pos >= counts[e]) return;
    int tok = tok_list[ci];
    int r = offsets[e] + pos;
    const float4* src = (const float4*)(x + (size_t)tok * DIM);
    uint2* dst = (uint2*)(xg + (size_t)r * DIM);
#pragma unroll
    for (int i = 0; i < 4; i++) {
        int idx = i * 64 + lane;
        float4 v = src[idx];
        uint2 o; o.x = packbf2(v.x, v.y); o.y = packbf2(v.z, v.w);
        dst[idx] = o;
    }
    if (lane == 0) prow[tok * 2 + klist[ci]] = r;
}

// ---------------- fc1: A(LDS) x W^T(streamed fp32->bf16), fused SiLU*val ----------------
// Block: 128 rows x (128 gate cols + 128 val cols). Wave w: cols [w*32, w*32+32).
__global__ __launch_bounds__(256, 2) void fc1_kernel(
    const __hip_bfloat16* __restrict__ xg, const float* __restrict__ fc1w,
    const float* __restrict__ fc1b,
    __hip_bfloat16* __restrict__ act,
    const int* __restrict__ counts, const int* __restrict__ offsets) {
    int e = blockIdx.z;
    int cnt = counts[e];
    int rt = blockIdx.y;
    if (rt * 128 >= cnt) return;
    int ct = blockIdx.x;                 // 0..31 over HID/128
    int row0 = offsets[e] + rt * 128;

    __shared__ __hip_bfloat16 As[128 * 64];

    int tid = threadIdx.x;
    int lane = tid & 63;
    int w = tid >> 6;
    int r = lane & 15, q = lane >> 4;

    const __hip_bfloat16* Abase = xg + (size_t)row0 * DIM;
    const float* Gbase = fc1w + ((size_t)e * TWO_H + (size_t)ct * 128) * DIM;
    const float* Vbase = Gbase + (size_t)HID * DIM;

    size_t offA[4]; int ldsA[4];
#pragma unroll
    for (int i = 0; i < 4; i++) {
        int c = w * 256 + i * 64 + lane;
        int m = c >> 3, kc = (c & 7) ^ (m & 7);      // XOR swizzle
        offA[i] = (size_t)m * DIM + kc * 8;
        ldsA[i] = (w * 256 + i * 64) * 8;
    }

    // B row pointers for this wave (one wave per 32-col slice, amp=1)
    const float* g0 = Gbase + (size_t)(w * 32 + r) * DIM;
    const float* g1 = Gbase + (size_t)(w * 32 + 16 + r) * DIM;
    const float* v0 = Vbase + (size_t)(w * 32 + r) * DIM;
    const float* v1 = Vbase + (size_t)(w * 32 + 16 + r) * DIM;

    f32x4 accg[8][2], accv[8][2];
#pragma unroll
    for (int a = 0; a < 8; a++)
#pragma unroll
        for (int b = 0; b < 2; b++)
#pragma unroll
            for (int k = 0; k < 4; k++) { accg[a][b][k] = 0.f; accv[a][b][k] = 0.f; }

    for (int kb = 0; kb < DIM / 64; ++kb) {
        int ko = kb * 64;
#pragma unroll
        for (int i = 0; i < 4; i++) async16(Abase + offA[i] + ko, (void*)(As + ldsA[i]));

        short8 bg[2][2], bv[2][2];
#pragma unroll
        for (int ks = 0; ks < 2; ks++) {
            int kk = ko + ks * 32 + q * 8;
            const float4* pg0 = (const float4*)(g0 + kk);
            const float4* pg1 = (const float4*)(g1 + kk);
            const float4* pv0 = (const float4*)(v0 + kk);
            const float4* pv1 = (const float4*)(v1 + kk);
            bg[ks][0] = cvtfrag(pg0[0], pg0[1]);
            bg[ks][1] = cvtfrag(pg1[0], pg1[1]);
            bv[ks][0] = cvtfrag(pv0[0], pv0[1]);
            bv[ks][1] = cvtfrag(pv1[0], pv1[1]);
        }
        __syncthreads();
#pragma unroll
        for (int ks = 0; ks < 2; ks++) {
            int swz = ((ks * 4 + q) ^ (lane & 7)) * 8;
#pragma unroll
            for (int ti = 0; ti < 8; ti++) {
                short8 af = *(const short8*)(As + (ti * 16 + r) * 64 + swz);
                accg[ti][0] = __builtin_amdgcn_mfma_f32_16x16x32_bf16(af, bg[ks][0], accg[ti][0], 0, 0, 0);
                accg[ti][1] = __builtin_amdgcn_mfma_f32_16x16x32_bf16(af, bg[ks][1], accg[ti][1], 0, 0, 0);
                accv[ti][0] = __builtin_amdgcn_mfma_f32_16x16x32_bf16(af, bv[ks][0], accv[ti][0], 0, 0, 0);
                accv[ti][1] = __builtin_amdgcn_mfma_f32_16x16x32_bf16(af, bv[ks][1], accv[ti][1], 0, 0, 0);
            }
        }
        __syncthreads();
    }

#pragma unroll
    for (int tj = 0; tj < 2; tj++) {
        int cg = ct * 128 + w * 32 + tj * 16 + r;    // col in [0,HID)
        float bg_ = fc1b[(size_t)e * TWO_H + cg];
        float bv_ = fc1b[(size_t)e * TWO_H + HID + cg];
#pragma unroll
        for (int ti = 0; ti < 8; ti++) {
#pragma unroll
            for (int rg = 0; rg < 4; rg++) {
                int lrow = ti * 16 + q * 4 + rg;
                if (rt * 128 + lrow < cnt) {
                    float gv = accg[ti][tj][rg] + bg_;
                    float vv = accv[ti][tj][rg] + bv_;
                    float sil = gv / (1.f + __expf(-gv));
                    act[(size_t)(row0 + lrow) * HID + cg] = __float2bfloat16(sil * vv);
                }
            }
        }
    }
}

// ---------------- fc2: act(LDS) x W2^T(streamed fp32->bf16) -> eout fp32 ----------------
// Block: 128 rows x 128 cols. Wave w: cols [w*32, w*32+32).
__global__ __launch_bounds__(256, 2) void fc2_kernel(
    const __hip_bfloat16* __restrict__ act, const float* __restrict__ fc2w,
    const float* __restrict__ fc2b,
    float* __restrict__ eout,
    const int* __restrict__ counts, const int* __restrict__ offsets) {
    int e = blockIdx.z;
    int cnt = counts[e];
    int rt = blockIdx.y;
    if (rt * 128 >= cnt) return;
    int ct = blockIdx.x;                 // 0..7 over DIM/128
    int row0 = offsets[e] + rt * 128;

    __shared__ __hip_bfloat16 As[128 * 64];

    int tid = threadIdx.x;
    int lane = tid & 63;
    int w = tid >> 6;
    int r = lane & 15, q = lane >> 4;

    const __hip_bfloat16* Abase = act + (size_t)row0 * HID;
    const float* Bbase = fc2w + ((size_t)e * DIM + (size_t)ct * 128) * HID;

    size_t offA[4]; int ldsA[4];
#pragma unroll
    for (int i = 0; i < 4; i++) {
        int c = w * 256 + i * 64 + lane;
        int m = c >> 3, kc = (c & 7) ^ (m & 7);
        offA[i] = (size_t)m * HID + kc * 8;
        ldsA[i] = (w * 256 + i * 64) * 8;
    }

    const float* b0 = Bbase + (size_t)(w * 32 + r) * HID;
    const float* b1 = Bbase + (size_t)(w * 32 + 16 + r) * HID;

    f32x4 acc[8][2];
#pragma unroll
    for (int a = 0; a < 8; a++)
#pragma unroll
        for (int b = 0; b < 2; b++)
#pragma unroll
            for (int k = 0; k < 4; k++) acc[a][b][k] = 0.f;

    for (int kb = 0; kb < HID / 64; ++kb) {
        int ko = kb * 64;
#pragma unroll
        for (int i = 0; i < 4; i++) async16(Abase + offA[i] + ko, (void*)(As + ldsA[i]));

        short8 bb[2][2];
#pragma unroll
        for (int ks = 0; ks < 2; ks++) {
            int kk = ko + ks * 32 + q * 8;
            const float4* p0 = (const float4*)(b0 + kk);
            const float4* p1 = (const float4*)(b1 + kk);
            bb[ks][0] = cvtfrag(p0[0], p0[1]);
            bb[ks][1] = cvtfrag(p1[0], p1[1]);
        }
        __syncthreads();
#pragma unroll
        for (int ks = 0; ks < 2; ks++) {
            int swz = ((ks * 4 + q) ^ (lane & 7)) * 8;
#pragma unroll
            for (int ti = 0; ti < 8; ti++) {
                short8 af = *(const short8*)(As + (ti * 16 + r) * 64 + swz);
                acc[ti][0] = __builtin_amdgcn_mfma_f32_16x16x32_bf16(af, bb[ks][0], acc[ti][0], 0, 0, 0);
                acc[ti][1] = __builtin_amdgcn_mfma_f32_16x16x32_bf16(af, bb[ks][1], acc[ti][1], 0, 0, 0);
            }
        }
        __syncthreads();
    }

#pragma unroll
    for (int tj = 0; tj < 2; tj++) {
        int col = ct * 128 + w * 32 + tj * 16 + r;
        float b_ = fc2b[(size_t)e * DIM + col];
#pragma unroll
        for (int ti = 0; ti < 8; ti++) {
#pragma unroll
            for (int rg = 0; rg < 4; rg++) {
                int lrow = ti * 16 + q * 4 + rg;
                if (rt * 128 + lrow < cnt)
                    eout[(size_t)(row0 + lrow) * DIM + col] = acc[ti][tj][rg] + b_;
            }
        }
    }
}

// ---------------- combine: y[n] = w0*eout[r0] + w1*eout[r1] ----------------
__global__ __launch_bounds__(256) void combine_kernel(const float* __restrict__ eout,
                                                      const int* __restrict__ prow,
                                                      const float* __restrict__ topw,
                                                      float* __restrict__ y) {
    int n = blockIdx.x;
    int t = threadIdx.x;
    int r0 = prow[2 * n], r1 = prow[2 * n + 1];
    float w0 = topw[2 * n], w1 = topw[2 * n + 1];
    const float4* a = (const float4*)(eout + (size_t)r0 * DIM);
    const float4* b = (const float4*)(eout + (size_t)r1 * DIM);
    float4 va = a[t], vb = b[t];
    float4 o;
    o.x = w0 * va.x + w1 * vb.x;
    o.y = w0 * va.y + w1 * vb.y;
    o.z = w0 * va.z + w1 * vb.z;
    o.w = w0 * va.w + w1 * vb.w;
    ((float4*)(y + (size_t)n * DIM))[t] = o;
}

extern "C" void kernel_launch(void* const* d_in, const int* in_sizes, int n_in,
                              void* d_out, int out_size, void* d_ws, size_t ws_size,
                              hipStream_t stream) {
    (void)in_sizes; (void)n_in; (void)out_size; (void)ws_size;
    const float* x = (const float*)d_in[0];
    const float* Wg = (const float*)d_in[1];
    const float* fc1w = (const float*)d_in[2];
    const float* fc1b = (const float*)d_in[3];
    const float* fc2w = (const float*)d_in[4];
    const float* fc2b = (const float*)d_in[5];
    float* out = (float*)d_out;

    char* wsp = (char*)d_ws;
    __hip_bfloat16* xg = (__hip_bfloat16*)wsp;   wsp += (size_t)ROWPAD * DIM * 2;
    __hip_bfloat16* act = (__hip_bfloat16*)wsp;  wsp += (size_t)ROWPAD * HID * 2;
    float* eout = (float*)wsp;                   wsp += (size_t)TOTROWS * DIM * 4;
    float* p = (float*)wsp;                      wsp += (size_t)NTOK * NEXP * 4;
    float* topw = (float*)wsp;                   wsp += (size_t)NTOK * 2 * 4;
    int* tok_list = (int*)wsp;                   wsp += (size_t)RCAP * 4;
    int* klist = (int*)wsp;                      wsp += (size_t)RCAP * 4;
    int* prow = (int*)wsp;                       wsp += (size_t)NTOK * 2 * 4;
    int* counts = (int*)wsp;                     wsp += 64;
    int* offsets = (int*)wsp;                    wsp += 64;

    hipMemsetAsync(counts, 0, 8 * sizeof(int), stream);
    gate_kernel<<<NTOK / 4, 256, 0, stream>>>(x, Wg, p, topw, tok_list, klist, counts);
    finalize_kernel<<<1, 256, 0, stream>>>(p, counts, offsets, out + (size_t)NTOK * DIM);
    pack_kernel<<<RCAP / 4, 256, 0, stream>>>(x, tok_list, klist, counts, offsets, xg, prow);
    fc1_kernel<<<dim3(HID / 128, 32, NEXP), 256, 0, stream>>>(xg, fc1w, fc1b, act, counts, offsets);
    fc2_kernel<<<dim3(DIM / 128, 32, NEXP), 256, 0, stream>>>(act, fc2w, fc2b, eout, counts, offsets);
    combine_kernel<<<NTOK, 256, 0, stream>>>(eout, prow, topw, out);
}

// Round 3
// 885.609 us; speedup vs baseline: 1.3551x; 1.3551x over previous
//
#include <hip/hip_runtime.h>
#include <hip/hip_bf16.h>
#include <cstdint>

#define NTOK 4096
#define DIM 1024
#define NEXP 8
#define HID 4096
#define TWO_H 8192
#define TOTROWS (NTOK*2)
#define ROWPAD (TOTROWS + 128)
#define GBLK (NTOK/4)

typedef __attribute__((ext_vector_type(8))) short short8;
typedef __attribute__((ext_vector_type(4))) float f32x4;

__device__ __forceinline__ void async16(const void* g, void* l) {
    __builtin_amdgcn_global_load_lds(
        (const __attribute__((address_space(1))) unsigned int*)g,
        (__attribute__((address_space(3))) unsigned int*)l, 16, 0, 0);
}

__device__ __forceinline__ unsigned int packbf2(float a, float b) {
    union { __hip_bfloat16 h[2]; unsigned int u; } t;
    t.h[0] = __float2bfloat16(a); t.h[1] = __float2bfloat16(b);
    return t.u;
}

// ---------------- convert both weight tensors fp32 -> bf16 ----------------
__global__ __launch_bounds__(256) void convert_kernel(const float* __restrict__ fc1w,
                                                      const float* __restrict__ fc2w,
                                                      __hip_bfloat16* __restrict__ w1b,
                                                      __hip_bfloat16* __restrict__ w2b) {
    const int n1 = NEXP * TWO_H * DIM / 8;   // 8,388,608 threads for fc1w
    int i = blockIdx.x * 256 + threadIdx.x;
    const float* s; __hip_bfloat16* d; int j;
    if (i < n1) { s = fc1w; d = w1b; j = i; }
    else        { s = fc2w; d = w2b; j = i - n1; }
    const float4* sp = (const float4*)s + (size_t)j * 2;
    float4 a = sp[0], b = sp[1];
    uint4 o;
    o.x = packbf2(a.x, a.y); o.y = packbf2(a.z, a.w);
    o.z = packbf2(b.x, b.y); o.w = packbf2(b.z, b.w);
    ((uint4*)d)[j] = o;
}

// ---------------- gate: logits, top-2, block hist + ranks, block psum ----------------
__global__ __launch_bounds__(256) void gate_kernel(
    const float* __restrict__ x, const float* __restrict__ Wg,
    float* __restrict__ topw, int* __restrict__ einfo,
    int* __restrict__ ghist, float* __restrict__ gpsum) {
    __shared__ float probs[4][8];
    __shared__ int epair[4][2];
    int wv = threadIdx.x >> 6;
    int lane = threadIdx.x & 63;
    int n = blockIdx.x * 4 + wv;
    const float* xr = x + (size_t)n * DIM;
    float acc[8];
#pragma unroll
    for (int e = 0; e < 8; e++) acc[e] = 0.f;
#pragma unroll
    for (int i = 0; i < 16; i++) {
        int d = i * 64 + lane;
        float xv = xr[d];
        const float4* wrow = (const float4*)(Wg + (size_t)d * 8);
        float4 w0 = wrow[0], w1 = wrow[1];
        acc[0] += xv * w0.x; acc[1] += xv * w0.y; acc[2] += xv * w0.z; acc[3] += xv * w0.w;
        acc[4] += xv * w1.x; acc[5] += xv * w1.y; acc[6] += xv * w1.z; acc[7] += xv * w1.w;
    }
#pragma unroll
    for (int m = 1; m < 64; m <<= 1) {
#pragma unroll
        for (int e = 0; e < 8; e++) acc[e] += __shfl_xor(acc[e], m, 64);
    }
    if (lane == 0) {
        int i0 = 0; float v0 = acc[0];
#pragma unroll
        for (int e = 1; e < 8; e++) if (acc[e] > v0) { v0 = acc[e]; i0 = e; }
        int i1 = -1; float v1 = -1e30f;
#pragma unroll
        for (int e = 0; e < 8; e++) if (e != i0 && acc[e] > v1) { v1 = acc[e]; i1 = e; }
        float ee = __expf(v1 - v0);
        float s = 1.f + ee;
        topw[2 * n] = 1.f / s;
        topw[2 * n + 1] = ee / s;
        float se = 0.f; float pe[8];
#pragma unroll
        for (int e = 0; e < 8; e++) { pe[e] = __expf(acc[e] - v0); se += pe[e]; }
        float inv = 1.f / se;
#pragma unroll
        for (int e = 0; e < 8; e++) probs[wv][e] = pe[e] * inv;
        epair[wv][0] = i0; epair[wv][1] = i1;
    }
    __syncthreads();
    int t = threadIdx.x;
    if (t < 8) {
        gpsum[blockIdx.x * 8 + t] = probs[0][t] + probs[1][t] + probs[2][t] + probs[3][t];
    }
    if (t == 0) {
        int h[8];
#pragma unroll
        for (int e = 0; e < 8; e++) h[e] = 0;
        int inf[4];
#pragma unroll
        for (int tt = 0; tt < 4; tt++) {
            int e0 = epair[tt][0], e1 = epair[tt][1];
            int r0 = h[e0]++, r1 = h[e1]++;
            inf[tt] = e0 | (e1 << 4) | (r0 << 8) | (r1 << 12);
        }
#pragma unroll
        for (int tt = 0; tt < 4; tt++) einfo[blockIdx.x * 4 + tt] = inf[tt];
#pragma unroll
        for (int e = 0; e < 8; e++) ghist[blockIdx.x * 8 + e] = h[e];
    }
}

// ---------------- scan: per-expert prefix over block hists, offsets, aux ----------------
__global__ __launch_bounds__(256) void scan_kernel(
    const int* __restrict__ ghist, const float* __restrict__ gpsum,
    int* __restrict__ gbase, int* __restrict__ counts, int* __restrict__ offsets,
    float* __restrict__ aux_out) {
    __shared__ int hist[GBLK * 8];
    __shared__ float psum[GBLK * 8];
    __shared__ int counts_s[8];
    __shared__ int offs[9];
    __shared__ float psum_e[8];
    int t = threadIdx.x;
    for (int i = t; i < GBLK * 8; i += 256) { hist[i] = ghist[i]; psum[i] = gpsum[i]; }
    __syncthreads();
    if (t < 8) {
        int run = 0;
        float ps = 0.f;
        for (int b = 0; b < GBLK; b++) {
            int v = hist[b * 8 + t];
            hist[b * 8 + t] = run;
            run += v;
            ps += psum[b * 8 + t];
        }
        counts_s[t] = run;
        psum_e[t] = ps;
    }
    __syncthreads();
    if (t == 0) {
        int off = 0; float aux = 0.f;
        for (int e = 0; e < 8; e++) {
            offs[e] = off;
            counts[e] = counts_s[e];
            offsets[e] = off;
            aux += ((float)counts_s[e] / (float)NTOK) * (psum_e[e] / (float)NTOK);
            off += counts_s[e];
        }
        offs[8] = off; offsets[8] = off;
        aux_out[0] = 8.f * aux;
    }
    __syncthreads();
    for (int i = t; i < GBLK * 8; i += 256) gbase[i] = hist[i] + offs[i & 7];
}

// ---------------- pack: gather token rows to both expert slots, fp32->bf16 ----------------
__global__ __launch_bounds__(256) void pack_kernel(const float* __restrict__ x,
                                                   const int* __restrict__ einfo,
                                                   const int* __restrict__ gbase,
                                                   __hip_bfloat16* __restrict__ xg,
                                                   int* __restrict__ rowinfo) {
    int wv = threadIdx.x >> 6;
    int lane = threadIdx.x & 63;
    int n = blockIdx.x * 4 + wv;
    int info = einfo[n];
    int e0 = info & 15, e1 = (info >> 4) & 15;
    int r0 = (info >> 8) & 15, r1 = (info >> 12) & 15;
    int blk = blockIdx.x;
    int row0 = gbase[blk * 8 + e0] + r0;
    int row1 = gbase[blk * 8 + e1] + r1;
    const float4* src = (const float4*)(x + (size_t)n * DIM);
    uint2* d0 = (uint2*)(xg + (size_t)row0 * DIM);
    uint2* d1 = (uint2*)(xg + (size_t)row1 * DIM);
#pragma unroll
    for (int i = 0; i < 4; i++) {
        int idx = i * 64 + lane;
        float4 v = src[idx];
        uint2 o; o.x = packbf2(v.x, v.y); o.y = packbf2(v.z, v.w);
        d0[idx] = o;
        d1[idx] = o;
    }
    if (lane == 0) {
        rowinfo[row0] = 2 * n;
        rowinfo[row1] = 2 * n + 1;
    }
}

// ---------------- fc1: A,Bg,Bv staged in LDS via async16; fused SiLU*val ----------------
__global__ __launch_bounds__(256, 2) void fc1_kernel(
    const __hip_bfloat16* __restrict__ xg, const __hip_bfloat16* __restrict__ w1b,
    const float* __restrict__ fc1b,
    __hip_bfloat16* __restrict__ act,
    const int* __restrict__ counts, const int* __restrict__ offsets) {
    int e = blockIdx.z;
    int cnt = counts[e];
    int rt = blockIdx.y;
    if (rt * 128 >= cnt) return;
    int ct = blockIdx.x;
    int row0 = offsets[e] + rt * 128;

    __shared__ __hip_bfloat16 As[128 * 64];
    __shared__ __hip_bfloat16 Bg[128 * 64];
    __shared__ __hip_bfloat16 Bv[128 * 64];

    int tid = threadIdx.x;
    int lane = tid & 63;
    int w = tid >> 6;
    int wr = w >> 1, wc = w & 1;
    int r = lane & 15, q = lane >> 4;

    const __hip_bfloat16* Abase = xg + (size_t)row0 * DIM;
    const __hip_bfloat16* Gbase = w1b + ((size_t)e * TWO_H + (size_t)ct * 128) * DIM;
    const __hip_bfloat16* Vbase = Gbase + (size_t)HID * DIM;

    size_t offA[4]; int ldsOff[4];
#pragma unroll
    for (int i = 0; i < 4; i++) {
        int c = w * 256 + i * 64 + lane;
        int m = c >> 3, kc = (c & 7) ^ (m & 7);   // XOR swizzle
        offA[i] = (size_t)m * DIM + kc * 8;
        ldsOff[i] = (w * 256 + i * 64) * 8;
    }

    f32x4 accg[4][4], accv[4][4];
#pragma unroll
    for (int a = 0; a < 4; a++)
#pragma unroll
        for (int b = 0; b < 4; b++)
#pragma unroll
            for (int k = 0; k < 4; k++) { accg[a][b][k] = 0.f; accv[a][b][k] = 0.f; }

    for (int kb = 0; kb < DIM / 64; ++kb) {
        size_t ko = (size_t)kb * 64;
#pragma unroll
        for (int i = 0; i < 4; i++) {
            async16(Abase + offA[i] + ko, (void*)(As + ldsOff[i]));
            async16(Gbase + offA[i] + ko, (void*)(Bg + ldsOff[i]));
            async16(Vbase + offA[i] + ko, (void*)(Bv + ldsOff[i]));
        }
        __syncthreads();
#pragma unroll
        for (int ks = 0; ks < 2; ks++) {
            short8 af[4], bg[4], bv[4];
            int swz = ((ks * 4 + q) ^ (lane & 7)) * 8;
#pragma unroll
            for (int ti = 0; ti < 4; ti++) {
                int m = wr * 64 + ti * 16 + r;
                af[ti] = *(const short8*)(As + m * 64 + swz);
            }
#pragma unroll
            for (int tj = 0; tj < 4; tj++) {
                int n = wc * 64 + tj * 16 + r;
                bg[tj] = *(const short8*)(Bg + n * 64 + swz);
                bv[tj] = *(const short8*)(Bv + n * 64 + swz);
            }
#pragma unroll
            for (int ti = 0; ti < 4; ti++)
#pragma unroll
                for (int tj = 0; tj < 4; tj++) {
                    accg[ti][tj] = __builtin_amdgcn_mfma_f32_16x16x32_bf16(af[ti], bg[tj], accg[ti][tj], 0, 0, 0);
                    accv[ti][tj] = __builtin_amdgcn_mfma_f32_16x16x32_bf16(af[ti], bv[tj], accv[ti][tj], 0, 0, 0);
                }
        }
        __syncthreads();
    }

    const float* bgate = fc1b + (size_t)e * TWO_H + (size_t)ct * 128;
    const float* bval = bgate + HID;
#pragma unroll
    for (int ti = 0; ti < 4; ti++) {
#pragma unroll
        for (int tj = 0; tj < 4; tj++) {
            int coln = wc * 64 + tj * 16 + r;
            float bg_ = bgate[coln];
            float bv_ = bval[coln];
            f32x4 g = accg[ti][tj], v = accv[ti][tj];
#pragma unroll
            for (int rg = 0; rg < 4; rg++) {
                int lrow = wr * 64 + ti * 16 + q * 4 + rg;
                if (rt * 128 + lrow < cnt) {
                    float gv = g[rg] + bg_;
                    float vv = v[rg] + bv_;
                    float sil = gv / (1.f + __expf(-gv));
                    act[(size_t)(row0 + lrow) * HID + (size_t)ct * 128 + coln] = __float2bfloat16(sil * vv);
                }
            }
        }
    }
}

// ---------------- fc2: act x W2^T -> scale by topw, atomicAdd into out ----------------
__global__ __launch_bounds__(256, 2) void fc2_kernel(
    const __hip_bfloat16* __restrict__ act, const __hip_bfloat16* __restrict__ w2b,
    const float* __restrict__ fc2b,
    const int* __restrict__ rowinfo, const float* __restrict__ topw,
    float* __restrict__ out,
    const int* __restrict__ counts, const int* __restrict__ offsets) {
    int e = blockIdx.z;
    int cnt = counts[e];
    int rt = blockIdx.y;
    if (rt * 128 >= cnt) return;
    int ct = blockIdx.x;
    int row0 = offsets[e] + rt * 128;

    __shared__ __hip_bfloat16 As[128 * 64];
    __shared__ __hip_bfloat16 Bs[128 * 64];

    int tid = threadIdx.x;
    int lane = tid & 63;
    int w = tid >> 6;
    int wr = w >> 1, wc = w & 1;
    int r = lane & 15, q = lane >> 4;

    const __hip_bfloat16* Abase = act + (size_t)row0 * HID;
    const __hip_bfloat16* Bbase = w2b + ((size_t)e * DIM + (size_t)ct * 128) * HID;

    size_t offA[4]; int ldsOff[4];
#pragma unroll
    for (int i = 0; i < 4; i++) {
        int c = w * 256 + i * 64 + lane;
        int m = c >> 3, kc = (c & 7) ^ (m & 7);
        offA[i] = (size_t)m * HID + kc * 8;
        ldsOff[i] = (w * 256 + i * 64) * 8;
    }

    f32x4 acc[4][4];
#pragma unroll
    for (int a = 0; a < 4; a++)
#pragma unroll
        for (int b = 0; b < 4; b++)
#pragma unroll
            for (int k = 0; k < 4; k++) acc[a][b][k] = 0.f;

    for (int kb = 0; kb < HID / 64; ++kb) {
        size_t ko = (size_t)kb * 64;
#pragma unroll
        for (int i = 0; i < 4; i++) {
            async16(Abase + offA[i] + ko, (void*)(As + ldsOff[i]));
            async16(Bbase + offA[i] + ko, (void*)(Bs + ldsOff[i]));
        }
        __syncthreads();
#pragma unroll
        for (int ks = 0; ks < 2; ks++) {
            short8 af[4], bf[4];
            int swz = ((ks * 4 + q) ^ (lane & 7)) * 8;
#pragma unroll
            for (int ti = 0; ti < 4; ti++) {
                int m = wr * 64 + ti * 16 + r;
                af[ti] = *(const short8*)(As + m * 64 + swz);
            }
#pragma unroll
            for (int tj = 0; tj < 4; tj++) {
                int n = wc * 64 + tj * 16 + r;
                bf[tj] = *(const short8*)(Bs + n * 64 + swz);
            }
#pragma unroll
            for (int ti = 0; ti < 4; ti++)
#pragma unroll
                for (int tj = 0; tj < 4; tj++)
                    acc[ti][tj] = __builtin_amdgcn_mfma_f32_16x16x32_bf16(af[ti], bf[tj], acc[ti][tj], 0, 0, 0);
        }
        __syncthreads();
    }

    const float* bias = fc2b + (size_t)e * DIM + (size_t)ct * 128;
#pragma unroll
    for (int ti = 0; ti < 4; ti++) {
        // per-row routing info (same for all tj)
        int inf[4]; float wgt[4]; int ok[4];
#pragma unroll
        for (int rg = 0; rg < 4; rg++) {
            int lrow = wr * 64 + ti * 16 + q * 4 + rg;
            ok[rg] = (rt * 128 + lrow < cnt);
            if (ok[rg]) {
                inf[rg] = rowinfo[row0 + lrow];
                wgt[rg] = topw[inf[rg]];
            }
        }
#pragma unroll
        for (int tj = 0; tj < 4; tj++) {
            int coln = wc * 64 + tj * 16 + r;
            float b_ = bias[coln];
            f32x4 a = acc[ti][tj];
#pragma unroll
            for (int rg = 0; rg < 4; rg++) {
                if (ok[rg]) {
                    int tok = inf[rg] >> 1;
                    atomicAdd(&out[(size_t)tok * DIM + (size_t)ct * 128 + coln],
                              wgt[rg] * (a[rg] + b_));
                }
            }
        }
    }
}

extern "C" void kernel_launch(void* const* d_in, const int* in_sizes, int n_in,
                              void* d_out, int out_size, void* d_ws, size_t ws_size,
                              hipStream_t stream) {
    (void)in_sizes; (void)n_in; (void)out_size; (void)ws_size;
    const float* x = (const float*)d_in[0];
    const float* Wg = (const float*)d_in[1];
    const float* fc1w = (const float*)d_in[2];
    const float* fc1b = (const float*)d_in[3];
    const float* fc2w = (const float*)d_in[4];
    const float* fc2b = (const float*)d_in[5];
    float* out = (float*)d_out;

    char* wsp = (char*)d_ws;
    __hip_bfloat16* w1b = (__hip_bfloat16*)wsp;  wsp += (size_t)NEXP * TWO_H * DIM * 2;
    __hip_bfloat16* w2b = (__hip_bfloat16*)wsp;  wsp += (size_t)NEXP * DIM * HID * 2;
    __hip_bfloat16* xg = (__hip_bfloat16*)wsp;   wsp += (size_t)ROWPAD * DIM * 2;
    __hip_bfloat16* act = (__hip_bfloat16*)wsp;  wsp += (size_t)ROWPAD * HID * 2;
    float* topw = (float*)wsp;                   wsp += (size_t)NTOK * 2 * 4;
    int* einfo = (int*)wsp;                      wsp += (size_t)NTOK * 4;
    int* ghist = (int*)wsp;                      wsp += (size_t)GBLK * 8 * 4;
    float* gpsum = (float*)wsp;                  wsp += (size_t)GBLK * 8 * 4;
    int* gbase = (int*)wsp;                      wsp += (size_t)GBLK * 8 * 4;
    int* rowinfo = (int*)wsp;                    wsp += (size_t)TOTROWS * 4;
    int* counts = (int*)wsp;                     wsp += 64;
    int* offsets = (int*)wsp;                    wsp += 64;

    // zero y region of out (fc2 accumulates atomically); aux written by scan
    hipMemsetAsync(out, 0, (size_t)NTOK * DIM * sizeof(float), stream);
    convert_kernel<<<49152, 256, 0, stream>>>(fc1w, fc2w, w1b, w2b);
    gate_kernel<<<GBLK, 256, 0, stream>>>(x, Wg, topw, einfo, ghist, gpsum);
    scan_kernel<<<1, 256, 0, stream>>>(ghist, gpsum, gbase, counts, offsets,
                                       out + (size_t)NTOK * DIM);
    pack_kernel<<<GBLK, 256, 0, stream>>>(x, einfo, gbase, xg, rowinfo);
    fc1_kernel<<<dim3(HID / 128, 32, NEXP), 256, 0, stream>>>(xg, w1b, fc1b, act, counts, offsets);
    fc2_kernel<<<dim3(DIM / 128, 32, NEXP), 256, 0, stream>>>(act, w2b, fc2b, rowinfo, topw,
                                                              out, counts, offsets);
}